// Round 1
// 198.194 us; speedup vs baseline: 1.0015x; 1.0015x over previous
//
#include <hip/hip_runtime.h>
#include <hip/hip_bf16.h>

// TwoLayerGraphSAGE on MI355X.
//   Bucketed counting-sort CSR build -> MFMA indicator-SpMM aggregation -> fused MFMA GEMMs.
// Layer-1 aggregation gathers fp8(e4m3) rows; layer-2 aggregation bf16.
// Aggregation (R1 rework): ONE 16-node group per WAVE (4 groups/block), no cross-wave
// reduction, 16KB LDS/block, <=64-reg budget (launch_bounds(256,8)) for 8 waves/SIMD.
// csr/ldst metadata for chunk ch+1 is issued BEFORE the vmcnt(0) gather drain so its
// latency overlaps instead of serializing the next iteration.
// GEMM: single fused kernel; h tile lives in LDS between layer 1 and layer 2.

#define N_NODES 100000
#define NGRP 6250         // N/16 node groups
#define NBKT 391          // ceil(100000/256) buckets of 256 dst nodes
#define ECHUNK 8192       // edges per block in hist/scatter
#define BCAP 12288        // LDS staging capacity per bucket
#define NXB 12500         // x-convert blocks
#define NWB 192           // weight-split blocks

typedef __attribute__((ext_vector_type(8))) short short8v;
typedef __attribute__((ext_vector_type(4))) float f32x4;
typedef __attribute__((ext_vector_type(2))) uint u32x2;

__device__ inline ushort bf16_rne(float f) {
    union { float f; uint u; } c; c.f = f;
    uint u = c.u;
    return (ushort)((u + 0x7FFFu + ((u >> 16) & 1u)) >> 16);
}
__device__ inline float bf16_f(ushort h) {
    union { uint u; float f; } c; c.u = (uint)h << 16;
    return c.f;
}
// f32 -> fp8 e4m3fn, RNE
__device__ inline unsigned char fp8_enc(float f) {
    union { float f; uint u; } c; c.f = f;
    uint u = c.u;
    uint s = (u >> 24) & 0x80u;
    uint a = u & 0x7FFFFFFFu;
    uint code;
    if (a >= 0x3C800000u) {
        uint r = a + 0x7FFFFu + ((a >> 20) & 1u);
        int e = (int)(r >> 23) - 120;
        uint mm = (r >> 20) & 7u;
        code = ((uint)e << 3) | mm;
        if (code > 0x7Eu) code = 0x7Eu;
    } else {
        code = (uint)(__uint_as_float(a) * 512.0f + 0.5f);
    }
    return (unsigned char)(s | code);
}

__device__ inline void gl_lds16(const void* g, void* l) {
    __builtin_amdgcn_global_load_lds(
        (const __attribute__((address_space(1))) uint*)g,
        (__attribute__((address_space(3))) uint*)l, 16, 0, 0);
}
__device__ inline uint lds_off(const void* p) {
    return (uint)(size_t)(const __attribute__((address_space(3))) char*)p;
}

// ---------------- fused prep: x->bf16+fp8 | weight split | bucket histogram ----------------
__global__ __launch_bounds__(256) void k_prep(const float* __restrict__ x,
                                              const float* __restrict__ W1l,
                                              const float* __restrict__ W1r,
                                              const float* __restrict__ W2l,
                                              const float* __restrict__ W2r,
                                              const int* __restrict__ dst, int E,
                                              ushort* __restrict__ xh,
                                              unsigned char* __restrict__ xf8,
                                              ushort* __restrict__ BT1h,
                                              ushort* __restrict__ BT1l,
                                              ushort* __restrict__ BT2h,
                                              ushort* __restrict__ BT2l,
                                              int* __restrict__ bhist) {
    __shared__ int hsh[NBKT];
    const int b = blockIdx.x;
    if (b < NXB) {
        int i = (b * 256 + threadIdx.x) * 4;
        float4 v = *(const float4*)&x[i];
        ushort4 hh;
        hh.x = bf16_rne(v.x); hh.y = bf16_rne(v.y);
        hh.z = bf16_rne(v.z); hh.w = bf16_rne(v.w);
        *(ushort4*)&xh[i] = hh;
        uint f8 = (uint)fp8_enc(v.x) | ((uint)fp8_enc(v.y) << 8) |
                  ((uint)fp8_enc(v.z) << 16) | ((uint)fp8_enc(v.w) << 24);
        *(uint*)&xf8[i] = f8;
    } else if (b < NXB + NWB) {
        int id = (b - NXB) * 256 + threadIdx.x;
        if (id < 32768) {
            int n = id >> 8, k = id & 255;
            float v = (k < 128) ? W1l[k * 128 + n] : W1r[(k - 128) * 128 + n];
            ushort h = bf16_rne(v);
            BT1h[id] = h;
            BT1l[id] = bf16_rne(v - bf16_f(h));
        } else {
            int i = id - 32768;
            int n = i >> 7, k = i & 127;
            float v = (n < 64) ? W2l[k * 64 + n] : W2r[k * 64 + (n - 64)];
            ushort h = bf16_rne(v);
            BT2h[i] = h;
            BT2l[i] = bf16_rne(v - bf16_f(h));
        }
    } else {
        int bb = b - NXB - NWB;
        for (int i = threadIdx.x; i < NBKT; i += 256) hsh[i] = 0;
        __syncthreads();
        int b0 = bb * ECHUNK;
        for (int i = threadIdx.x; i < ECHUNK; i += 256) {
            int e = b0 + i;
            if (e < E) atomicAdd(&hsh[dst[e] >> 8], 1);
        }
        __syncthreads();
        for (int i = threadIdx.x; i < NBKT; i += 256)
            if (hsh[i]) atomicAdd(&bhist[i], hsh[i]);
    }
}

// ---------------- A2: scan bucket totals ----------------
__global__ __launch_bounds__(512) void kA2_scan(const int* __restrict__ bhist,
                                                int* __restrict__ boff,
                                                int* __restrict__ bcur) {
    __shared__ int s[512];
    int t = threadIdx.x;
    s[t] = (t < NBKT) ? bhist[t] : 0;
    __syncthreads();
    for (int d = 1; d < 512; d <<= 1) {
        int v = (t >= d) ? s[t - d] : 0;
        __syncthreads();
        s[t] += v;
        __syncthreads();
    }
    if (t <= NBKT) {
        int e = (t == 0) ? 0 : s[t - 1];
        boff[t] = e;
        if (t < NBKT) bcur[t] = e;
    }
}

// ---------------- A3: scatter packed (src | dlow<<17) ----------------
__global__ __launch_bounds__(256) void kA3_scatter(const int* __restrict__ src,
                                                   const int* __restrict__ dst,
                                                   int* __restrict__ bcur,
                                                   int* __restrict__ pairs, int E) {
    __shared__ int hist[NBKT];
    __shared__ int base[NBKT];
    __shared__ ushort rank[ECHUNK];
    for (int i = threadIdx.x; i < NBKT; i += 256) hist[i] = 0;
    __syncthreads();
    int b0 = blockIdx.x * ECHUNK;
    for (int i = threadIdx.x; i < ECHUNK; i += 256) {
        int e = b0 + i;
        if (e < E) rank[i] = (ushort)atomicAdd(&hist[dst[e] >> 8], 1);
    }
    __syncthreads();
    for (int i = threadIdx.x; i < NBKT; i += 256) {
        int c = hist[i];
        base[i] = c ? atomicAdd(&bcur[i], c) : 0;
    }
    __syncthreads();
    for (int i = threadIdx.x; i < ECHUNK; i += 256) {
        int e = b0 + i;
        if (e < E) {
            int d = dst[e];
            pairs[base[d >> 8] + rank[i]] = src[e] | ((d & 255) << 17);
        }
    }
}

// ---------------- B: per-bucket local sort -> csr, ldst, offsets, invdeg ----------------
__global__ __launch_bounds__(256) void kB_build(const int* __restrict__ pairs,
                                                const int* __restrict__ boff,
                                                int* __restrict__ csr,
                                                unsigned char* __restrict__ ldst,
                                                int* __restrict__ offsets,
                                                float* __restrict__ invdeg,
                                                int N, int E) {
    __shared__ int cnt[256];
    __shared__ int sc[256];
    __shared__ int cur[256];
    __shared__ int stage[BCAP];
    const int b = blockIdx.x;
    const int gbase = boff[b], gcount = boff[b + 1] - gbase;
    const int n0 = b << 8;
    const int t = threadIdx.x;

    cnt[t] = 0;
    __syncthreads();
    for (int i = t; i < gcount; i += 256)
        atomicAdd(&cnt[pairs[gbase + i] >> 17], 1);
    __syncthreads();
    sc[t] = cnt[t];
    __syncthreads();
    for (int d = 1; d < 256; d <<= 1) {
        int v = (t >= d) ? sc[t - d] : 0;
        __syncthreads();
        sc[t] += v;
        __syncthreads();
    }
    int excl = sc[t] - cnt[t];
    cur[t] = excl;
    int node = n0 + t;
    if (node < N) {
        offsets[node] = gbase + excl;
        invdeg[node] = 1.0f / fmaxf((float)cnt[t], 1.0f);
    }
    if (b == NBKT - 1 && t == 0) offsets[N] = E;
    __syncthreads();

    if (gcount <= BCAP) {
        for (int i = t; i < gcount; i += 256) {
            int p = pairs[gbase + i];
            int pos = atomicAdd(&cur[p >> 17], 1);
            stage[pos] = p;
        }
        __syncthreads();
        for (int i = t; i < gcount; i += 256) {
            int p = stage[i];
            csr[gbase + i] = p & 0x1FFFF;
            ldst[gbase + i] = (unsigned char)((p >> 17) & 15);
        }
    } else {
        for (int i = t; i < gcount; i += 256) {
            int p = pairs[gbase + i];
            int pos = atomicAdd(&cur[p >> 17], 1);
            csr[gbase + pos] = p & 0x1FFFF;
            ldst[gbase + pos] = (unsigned char)((p >> 17) & 15);
        }
    }
}

// ============ layer-1 MFMA indicator-SpMM aggregation, fp8 ============
// ONE 16-node group per WAVE (4 groups per block). Private acc per wave,
// no cross-wave reduction, no barriers. 4KB staging per wave.
// tr-read/MFMA cluster split into 2x4 tiles to keep reg budget <=64
// (8 waves/SIMD with __launch_bounds__(256,8); unified VGPR/AGPR file).
__global__ __launch_bounds__(256, 8) void k_agg1(const unsigned char* __restrict__ xf8,
                                                 const int* __restrict__ csr,
                                                 const unsigned char* __restrict__ ldst,
                                                 const int* __restrict__ off,
                                                 const float* __restrict__ invdeg,
                                                 ushort* __restrict__ ah, int E) {
    __shared__ char smem[16384];   // 4KB staging per wave
    const int wv = threadIdx.x >> 6, lane = threadIdx.x & 63;
    const int g = blockIdx.x * 4 + wv;
    if (g >= NGRP) return;
    const int gbase = off[g * 16], gend = off[g * 16 + 16];
    const int cnt = gend - gbase;
    const int m = lane & 15;
    const int e_meta = lane & 31;
    const int t_hi = lane >> 5;
    const int Emax = E - 1;
    char* stg = smem + wv * 4096;

    f32x4 acc[8] = {};
    const int nch = (cnt + 31) >> 5;

    int pe = gbase + e_meta;
    int se = csr[(pe < Emax) ? pe : Emax];
    int lb = (pe < gend) ? (int)ldst[pe] : 255;

    for (int ch = 0; ch < nch; ++ch) {
        const char* rowbase = (const char*)xf8 + (size_t)se * 128;
        #pragma unroll
        for (int c = 0; c < 4; ++c)
            gl_lds16(rowbase + (c * 2 + t_hi) * 16, stg + c * 1024);

        // prefetch next chunk's metadata BEFORE the drain: its latency overlaps
        // the gather drain (max, not sum) and se is retired by next iteration.
        int p = gbase + (ch + 1) * 32 + e_meta;
        se = csr[(p < Emax) ? p : Emax];
        int lbn = (p < gend) ? (int)ldst[p] : 255;

        asm volatile("s_waitcnt vmcnt(0)" ::: "memory");
        __builtin_amdgcn_sched_barrier(0);

        unsigned long long av = 0ull;
        #pragma unroll
        for (int j = 0; j < 8; ++j) {
            int k = (lane >> 4) * 8 + j;
            int b = __shfl(lb, k);
            av |= (b == m) ? (0x38ull << (8 * j)) : 0ull;
        }

        uint base0 = lds_off(stg) + lane * 8;
        #pragma unroll
        for (int th = 0; th < 2; ++th) {
            u32x2 tb[4];
            #pragma unroll
            for (int t = 0; t < 4; ++t) {
                uint a1 = base0 + (th * 4 + t) * 512;
                asm volatile("ds_read_b64_tr_b8 %0, %1" : "=v"(tb[t]) : "v"(a1));
            }
            asm volatile("s_waitcnt lgkmcnt(0)" ::: "memory");
            __builtin_amdgcn_sched_barrier(0);
            #pragma unroll
            for (int t = 0; t < 4; ++t) {
                unsigned long long bv = ((unsigned long long)tb[t].y << 32) | tb[t].x;
                acc[th * 4 + t] = __builtin_amdgcn_mfma_f32_16x16x32_fp8_fp8(
                    (long long)av, (long long)bv, acc[th * 4 + t], 0, 0, 0);
            }
            __builtin_amdgcn_sched_barrier(0);  // keep halves separate (reg reuse)
        }
        lb = lbn;
    }

    float idv[4];
    #pragma unroll
    for (int i = 0; i < 4; ++i) idv[i] = invdeg[g * 16 + (lane >> 4) * 4 + i];
    #pragma unroll
    for (int t = 0; t < 8; ++t) {
        #pragma unroll
        for (int i = 0; i < 4; ++i) {
            int node = g * 16 + (lane >> 4) * 4 + i;
            ah[(size_t)node * 128 + t * 16 + m] = bf16_rne(acc[t][i] * idv[i]);
        }
    }
}

// ============ layer-2 aggregation + combine (bf16, tr_b16), same wave-per-group scheme ============
__global__ __launch_bounds__(256, 8) void k_agg2(const ushort* __restrict__ hWl,
                                                 const float* __restrict__ hWr,
                                                 const int* __restrict__ csr,
                                                 const unsigned char* __restrict__ ldst,
                                                 const int* __restrict__ off,
                                                 const float* __restrict__ invdeg,
                                                 const float* __restrict__ b2,
                                                 float* __restrict__ out, int E) {
    __shared__ char smem[16384];   // 4KB staging per wave
    const int wv = threadIdx.x >> 6, lane = threadIdx.x & 63;
    const int g = blockIdx.x * 4 + wv;
    if (g >= NGRP) return;
    const int gbase = off[g * 16], gend = off[g * 16 + 16];
    const int cnt = gend - gbase;
    const int m = lane & 15;
    const int phys = lane >> 3;
    const int E4 = (phys < 4) ? phys * 2 : (phys - 4) * 2 + 1;
    const int e_st = E4 * 4 + ((lane >> 1) & 3);
    const int e_meta = lane & 31;
    const int Emax = E - 1;
    char* stg = smem + wv * 4096;

    f32x4 acc[4] = {};
    const int nch = (cnt + 31) >> 5;

    int ps = gbase + e_st;
    int se = csr[(ps < Emax) ? ps : Emax];
    int pm = gbase + e_meta;
    int lb = (pm < gend) ? (int)ldst[pm] : 255;

    for (int ch = 0; ch < nch; ++ch) {
        const char* gsrc = (const char*)hWl + (size_t)se * 128 + (lane & 1) * 16;
        #pragma unroll
        for (int c = 0; c < 4; ++c)
            gl_lds16(gsrc + c * 32, stg + c * 1024);

        int p = gbase + (ch + 1) * 32;
        int ps2 = p + e_st;
        se = csr[(ps2 < Emax) ? ps2 : Emax];
        int pm2 = p + e_meta;
        int lbn = (pm2 < gend) ? (int)ldst[pm2] : 255;

        asm volatile("s_waitcnt vmcnt(0)" ::: "memory");
        __builtin_amdgcn_sched_barrier(0);

        uint au[4];
        #pragma unroll
        for (int jp = 0; jp < 4; ++jp) {
            int k0 = (lane >> 4) * 8 + jp * 2;
            int b0 = __shfl(lb, k0);
            int b1 = __shfl(lb, k0 + 1);
            au[jp] = ((b0 == m) ? 0x3F80u : 0u) | (((b1 == m) ? 0x3F80u : 0u) << 16);
        }
        union { uint u[4]; short8v v; } A_;
        A_.u[0] = au[0]; A_.u[1] = au[1]; A_.u[2] = au[2]; A_.u[3] = au[3];

        uint base0 = lds_off(stg) + lane * 8;
        #pragma unroll
        for (int th = 0; th < 2; ++th) {
            u32x2 t1[2], t2[2];
            #pragma unroll
            for (int t = 0; t < 2; ++t) {
                uint a1 = base0 + (th * 2 + t) * 1024;
                uint a2 = a1 + 512;
                asm volatile("ds_read_b64_tr_b16 %0, %1" : "=v"(t1[t]) : "v"(a1));
                asm volatile("ds_read_b64_tr_b16 %0, %1" : "=v"(t2[t]) : "v"(a2));
            }
            asm volatile("s_waitcnt lgkmcnt(0)" ::: "memory");
            __builtin_amdgcn_sched_barrier(0);
            #pragma unroll
            for (int t = 0; t < 2; ++t) {
                union { uint u[4]; short8v v; } B_;
                B_.u[0] = t1[t].x; B_.u[1] = t1[t].y;
                B_.u[2] = t2[t].x; B_.u[3] = t2[t].y;
                acc[th * 2 + t] = __builtin_amdgcn_mfma_f32_16x16x32_bf16(
                    A_.v, B_.v, acc[th * 2 + t], 0, 0, 0);
            }
            __builtin_amdgcn_sched_barrier(0);  // keep halves separate (reg reuse)
        }
        lb = lbn;
    }

    float idv[4];
    #pragma unroll
    for (int i = 0; i < 4; ++i) idv[i] = invdeg[g * 16 + (lane >> 4) * 4 + i];
    #pragma unroll
    for (int t = 0; t < 4; ++t) {
        #pragma unroll
        for (int i = 0; i < 4; ++i) {
            int node = g * 16 + (lane >> 4) * 4 + i;
            size_t idx = (size_t)node * 64 + t * 16 + m;
            out[idx] = acc[t][i] * idv[i] + hWr[idx] + b2[t * 16 + m];
        }
    }
}

// ---------------- fused MFMA GEMM: layer1 -> h (LDS) -> layer2 ----------------
// BM=128, 4 waves (2x2), 64x64/wave. LDS rows padded to 40 halves (80B).
// Phase 1: [agg|x] @ BT1(hi+lo), relu(+b1) -> hT in LDS (chunked [kc][row][40]).
// Phase 2: hT @ BT2(hi+lo) -> hWl (bf16), hWr (f32). h never touches global.
__global__ __launch_bounds__(256) void k_mfma12(
    const ushort* __restrict__ Agg, const ushort* __restrict__ X,
    const ushort* __restrict__ B1h, const ushort* __restrict__ B1l,
    const ushort* __restrict__ B2h, const ushort* __restrict__ B2l,
    const float* __restrict__ b1,
    ushort* __restrict__ hWl, float* __restrict__ hWr, int M) {
    __shared__ ushort Ah[128 * 40], Bh[128 * 40], Bl[128 * 40];
    __shared__ ushort hT[4 * 128 * 40];

    const int tid = threadIdx.x;
    const int wid = tid >> 6, lane = tid & 63;
    const int wm = wid >> 1, wn = wid & 1;
    const int m0 = blockIdx.x * 128;
    const int rl = lane & 15, kof = (lane >> 4) * 8;
    const int rq = lane >> 4;

    // ---------- phase 1: K=256 over [agg | x] ----------
    f32x4 acc[4][4] = {};
    for (int kc = 0; kc < 8; ++kc) {
        #pragma unroll
        for (int r = 0; r < 2; ++r) {
            int chunk = tid + 256 * r;
            int row = chunk >> 2, cq = chunk & 3;
            int gk = kc * 32 + cq * 8;
            int ldso = row * 40 + cq * 8;
            int grow = m0 + row;
            if (grow >= M) grow = M - 1;
            if (gk >= 128) {
                *(short8v*)&Ah[ldso] = *(const short8v*)&X[(size_t)grow * 128 + gk - 128];
            } else {
                *(short8v*)&Ah[ldso] = *(const short8v*)&Agg[(size_t)grow * 128 + gk];
            }
            *(short8v*)&Bh[ldso] = *(const short8v*)&B1h[row * 256 + gk];
            *(short8v*)&Bl[ldso] = *(const short8v*)&B1l[row * 256 + gk];
        }
        __syncthreads();

        short8v a_h[4], b_h[4], b_l[4];
        #pragma unroll
        for (int f = 0; f < 4; ++f) {
            int ra = wm * 64 + f * 16 + rl;
            int rb = wn * 64 + f * 16 + rl;
            a_h[f] = *(const short8v*)&Ah[ra * 40 + kof];
            b_h[f] = *(const short8v*)&Bh[rb * 40 + kof];
            b_l[f] = *(const short8v*)&Bl[rb * 40 + kof];
        }
        #pragma unroll
        for (int mf = 0; mf < 4; ++mf)
            #pragma unroll
            for (int nf = 0; nf < 4; ++nf) {
                acc[mf][nf] = __builtin_amdgcn_mfma_f32_16x16x32_bf16(a_h[mf], b_h[nf], acc[mf][nf], 0, 0, 0);
                acc[mf][nf] = __builtin_amdgcn_mfma_f32_16x16x32_bf16(a_h[mf], b_l[nf], acc[mf][nf], 0, 0, 0);
            }
        __syncthreads();
    }

    // ---------- h tile -> LDS (relu + bias, bf16) ----------
    #pragma unroll
    for (int mf = 0; mf < 4; ++mf)
        #pragma unroll
        for (int nf = 0; nf < 4; ++nf) {
            int col = wn * 64 + nf * 16 + rl;
            float bv = b1[col];
            #pragma unroll
            for (int i = 0; i < 4; ++i) {
                int rloc = wm * 64 + mf * 16 + rq * 4 + i;
                float v = fmaxf(acc[mf][nf][i] + bv, 0.0f);
                hT[((col >> 5) * 128 + rloc) * 40 + (col & 31)] = bf16_rne(v);
            }
        }
    __syncthreads();

    // ---------- phase 2: K=128 over h ----------
    f32x4 acc2[4][4] = {};
    for (int kc = 0; kc < 4; ++kc) {
        #pragma unroll
        for (int r = 0; r < 2; ++r) {
            int chunk = tid + 256 * r;
            int row = chunk >> 2, cq = chunk & 3;
            int gk = kc * 32 + cq * 8;
            int ldso = row * 40 + cq * 8;
            *(short8v*)&Bh[ldso] = *(const short8v*)&B2h[row * 128 + gk];
            *(short8v*)&Bl[ldso] = *(const short8v*)&B2l[row * 128 + gk];
        }
        __syncthreads();

        short8v a_h[4], b_h[4], b_l[4];
        #pragma unroll
        for (int f = 0; f < 4; ++f) {
            int ra = wm * 64 + f * 16 + rl;
            int rb = wn * 64 + f * 16 + rl;
            a_h[f] = *(const short8v*)&hT[(kc * 128 + ra) * 40 + kof];
            b_h[f] = *(const short8v*)&Bh[rb * 40 + kof];
            b_l[f] = *(const short8v*)&Bl[rb * 40 + kof];
        }
        #pragma unroll
        for (int mf = 0; mf < 4; ++mf)
            #pragma unroll
            for (int nf = 0; nf < 4; ++nf) {
                acc2[mf][nf] = __builtin_amdgcn_mfma_f32_16x16x32_bf16(a_h[mf], b_h[nf], acc2[mf][nf], 0, 0, 0);
                acc2[mf][nf] = __builtin_amdgcn_mfma_f32_16x16x32_bf16(a_h[mf], b_l[nf], acc2[mf][nf], 0, 0, 0);
            }
        __syncthreads();
    }

    // ---------- epilogue: hWl (bf16) | hWr (f32) ----------
    #pragma unroll
    for (int mf = 0; mf < 4; ++mf)
        #pragma unroll
        for (int nf = 0; nf < 4; ++nf) {
            int col = wn * 64 + nf * 16 + rl;
            #pragma unroll
            for (int i = 0; i < 4; ++i) {
                int row = m0 + wm * 64 + mf * 16 + rq * 4 + i;
                if (row < M) {
                    float v = acc2[mf][nf][i];
                    if (col < 64) hWl[(size_t)row * 64 + col] = bf16_rne(v);
                    else          hWr[(size_t)row * 64 + col - 64] = v;
                }
            }
        }
}

extern "C" void kernel_launch(void* const* d_in, const int* in_sizes, int n_in,
                              void* d_out, int out_size, void* d_ws, size_t ws_size,
                              hipStream_t stream) {
    const float* x   = (const float*)d_in[0];
    const int*   ei  = (const int*)d_in[1];
    const float* W1l = (const float*)d_in[3];
    const float* W1r = (const float*)d_in[4];
    const float* b1  = (const float*)d_in[5];
    const float* W2l = (const float*)d_in[6];
    const float* W2r = (const float*)d_in[7];
    const float* b2  = (const float*)d_in[8];
    float* out = (float*)d_out;

    const int N = N_NODES;
    const int E = in_sizes[1] / 2;     // 1,600,000
    const int* src = ei;
    const int* dst = ei + E;
    const int NEB = (E + ECHUNK - 1) / ECHUNK;   // 196

    // workspace layout (bytes)
    char* ws = (char*)d_ws;
    int*           bhist   = (int*)   (ws + 0);
    int*           boff    = (int*)   (ws + 4096);
    int*           bcur    = (int*)   (ws + 8192);
    int*           offsets = (int*)   (ws + 12288);      // N+1
    float*         invdeg  = (float*) (ws + 417792);     // N
    int*           csr     = (int*)   (ws + 819200);     // E ints (6.4MB)
    unsigned char* ldst    = (unsigned char*)(ws + 7220224);  // E bytes (1.6MB)
    unsigned char* x_f8    = (unsigned char*)(ws + 8821760);  // N*128 fp8 (12.8MB)
    ushort*        x_hi    = (ushort*)(ws + 21622784);   // 25.6MB
    ushort*        agg_hi  = (ushort*)(ws + 47223808);   // 25.6MB
    float*         hWr     = (float*) (ws + 98425856);   // 25.6MB
    ushort*        BT1h    = (ushort*)(ws + 124026880);  // 64KB
    ushort*        BT1l    = (ushort*)(ws + 124092416);
    ushort*        BT2h    = (ushort*)(ws + 124157952);  // 32KB
    ushort*        BT2l    = (ushort*)(ws + 124190720);
    // pairs (packed int, 6.4MB) aliases the hWr slot (dead before mfma12 writes hWr)
    int*           pairs   = (int*)   (ws + 98425856);
    // hWl lives in its own slot (must not alias agg: mfma12 reads agg while writing hWl)
    ushort*        hWl     = (ushort*)(ws + 72824832);   // 12.8MB used

    hipMemsetAsync(bhist, 0, NBKT * 4, stream);

    k_prep<<<NXB + NWB + NEB, 256, 0, stream>>>(x, W1l, W1r, W2l, W2r, dst, E,
                                                x_hi, x_f8, BT1h, BT1l, BT2h, BT2l, bhist);
    kA2_scan<<<1, 512, 0, stream>>>(bhist, boff, bcur);
    kA3_scatter<<<NEB, 256, 0, stream>>>(src, dst, bcur, pairs, E);
    kB_build<<<NBKT, 256, 0, stream>>>(pairs, boff, csr, ldst, offsets, invdeg, N, E);

    const int GAGG = (NGRP + 3) / 4;   // 1563 blocks, 4 groups (waves) each
    k_agg1<<<GAGG, 256, 0, stream>>>(x_f8, csr, ldst, offsets, invdeg, agg_hi, E);

    const int MB = (N + 127) / 128;    // 782
    k_mfma12<<<MB, 256, 0, stream>>>(agg_hi, x_hi, BT1h, BT1l, BT2h, BT2l,
                                     b1, hWl, hWr, N);

    k_agg2<<<GAGG, 256, 0, stream>>>(hWl, hWr, csr, ldst, offsets, invdeg, b2, out, E);
}